// Round 1
// baseline (4602.061 us; speedup 1.0000x reference)
//
#include <hip/hip_runtime.h>
#include <stdint.h>

typedef unsigned short u16;
typedef uint32_t u32;
typedef __attribute__((ext_vector_type(4))) u32 u32x4;
typedef __attribute__((ext_vector_type(8))) short v8s;
typedef __attribute__((ext_vector_type(4))) float f32x4;

// ---------------- workspace layout (bytes) ----------------
// flags : u32 [512][64]                     @ 0        (131072 B)
// h_hi  : u16 [2][64][512]                  @ 131072   (131072 B)
// h_lo  : u16 [2][64][512]                  @ 262144   (131072 B)
// wfrag : u16 [64][2][24][64][16]           @ 393216   (6291456 B)
//         (per (wg,ntile,chunk,lane): 8 hi shorts + 8 lo shorts)
#define OFF_FLAGS 0
#define OFF_HHI   131072
#define OFF_HLO   262144
#define OFF_WF    393216

__device__ __forceinline__ u16 bf_hi(float v) {
  return (u16)(__builtin_bit_cast(u32, v) >> 16);
}
__device__ __forceinline__ float bf_up(u16 h) {
  return __builtin_bit_cast(float, (u32)h << 16);
}
__device__ __forceinline__ float tanhf_fast(float x) {
  float e = __expf(2.f * x);
  return 1.f - 2.f / (e + 1.f);
}
__device__ __forceinline__ float sigm(float x) {
  return 1.f / (1.f + __expf(-x));
}

// ---------------- init: zero flags + h buffers, set flags row 0 ----------------
__global__ void k_init(u32* w) {
  int i = blockIdx.x * 256 + threadIdx.x;   // 98304 u32 total (flags + h_hi + h_lo)
  if (i < 98304) w[i] = (i < 64) ? 1u : 0u; // flags[0][0..63] = 1 (h0 ready)
}

// ---------------- pre-pack W_ih / W_hh into MFMA fragment order, bf16 hi/lo ----
// chunk c: 0..7 -> W_ih (K'=c*32), 8..23 -> W_hh (K=(c-8)*32)
// B[k][n32] = W[R(n32)][k], R(n32) = (n32>>3)*512 + wg*8 + (n32&7)  (i,f,g,o blocks)
__global__ void k_prep(const float* __restrict__ Wih, const float* __restrict__ Whh,
                       u16* __restrict__ wf) {
  int idx = blockIdx.x * 256 + threadIdx.x;
  if (idx >= 64 * 2 * 24 * 64) return;
  int lane = idx & 63;
  int r1 = idx >> 6;
  int c  = r1 % 24;
  int r2 = r1 / 24;
  int nt = r2 & 1;
  int wg = r2 >> 1;
  int n32 = nt * 16 + (lane & 15);
  int R = (n32 >> 3) * 512 + wg * 8 + (n32 & 7);
  int gq = lane >> 4;
  const float* src = (c < 8) ? (Wih + (size_t)R * 256 + c * 32 + 8 * gq)
                             : (Whh + (size_t)R * 512 + (c - 8) * 32 + 8 * gq);
  u16* d = wf + (size_t)idx * 16;
#pragma unroll
  for (int i = 0; i < 8; ++i) {
    float v = src[i];
    u16 hi = bf_hi(v);
    float lo = v - bf_up(hi);
    d[i] = hi;
    d[8 + i] = bf_hi(lo);
  }
}

// ---------------- load/store helpers (inline asm) ----------------
#define LOADG(DST, PTR) \
  asm volatile("global_load_dwordx4 %0, %1, off" : "=v"(DST) : "v"(PTR))
#define LOADC(DST, PTR) \
  asm volatile("global_load_dwordx4 %0, %1, off sc0 sc1" : "=v"(DST) : "v"(PTR))
#define STORES_C(PTR, VAL) \
  asm volatile("global_store_short %0, %1, off sc0 sc1" :: "v"(PTR), "v"(VAL) : "memory")

#define MFMA16(a, b, c) __builtin_amdgcn_mfma_f32_16x16x32_bf16((a), (b), (c), 0, 0, 0)

// B-frag loads for chunk (wv + 4*J) into RG[8..11]
#define ISSUE_B(J, RG) { \
  const u16* pb0_ = wf + ((((size_t)wg * 2 + 0) * 24 + (wv + 4 * (J))) * 64 + lane) * 16; \
  const u16* pb1_ = wf + ((((size_t)wg * 2 + 1) * 24 + (wv + 4 * (J))) * 64 + lane) * 16; \
  LOADG(RG[8], pb0_);  LOADG(RG[9], pb0_ + 8); \
  LOADG(RG[10], pb1_); LOADG(RG[11], pb1_ + 8); }

// emb chunk: A = fp32 embedding rows (gathered), 8 consecutive k' per lane
#define ISSUE_E(J, RG) { \
  const int ko_ = (wv + 4 * (J)) * 32 + 8 * gq; \
  LOADG(RG[0], ebase0 + ko_); LOADG(RG[1], ebase0 + ko_ + 4); \
  LOADG(RG[2], ebase1 + ko_); LOADG(RG[3], ebase1 + ko_ + 4); \
  LOADG(RG[4], ebase2 + ko_); LOADG(RG[5], ebase2 + ko_ + 4); \
  LOADG(RG[6], ebase3 + ko_); LOADG(RG[7], ebase3 + ko_ + 4); \
  ISSUE_B(J, RG); }

// h chunk: A = bf16 hi/lo of h_prev, coherent loads (cross-XCD)
#define ISSUE_H(J, RG) { \
  const int ko_ = ((wv + 4 * (J)) - 8) * 32 + 8 * gq; \
  LOADC(RG[0], hc_hi + (0 * 16 + cl) * 512 + ko_); LOADC(RG[1], hc_lo + (0 * 16 + cl) * 512 + ko_); \
  LOADC(RG[2], hc_hi + (1 * 16 + cl) * 512 + ko_); LOADC(RG[3], hc_lo + (1 * 16 + cl) * 512 + ko_); \
  LOADC(RG[4], hc_hi + (2 * 16 + cl) * 512 + ko_); LOADC(RG[5], hc_lo + (2 * 16 + cl) * 512 + ko_); \
  LOADC(RG[6], hc_hi + (3 * 16 + cl) * 512 + ko_); LOADC(RG[7], hc_lo + (3 * 16 + cl) * 512 + ko_); \
  ISSUE_B(J, RG); }

// fp32x8 -> bf16 hi/lo fragments (truncation hi + bf16(lo) keeps ~2^-17 rel)
#define CVT8(RG0, RG1, AH, AL) { \
  _Pragma("unroll") for (int i_ = 0; i_ < 4; ++i_) { \
    u32 u0_ = (RG0)[i_]; float f0_ = __builtin_bit_cast(float, u0_); \
    float h0_ = __builtin_bit_cast(float, u0_ & 0xffff0000u); \
    (AH)[i_] = (short)(u0_ >> 16); \
    (AL)[i_] = (short)(__builtin_bit_cast(u32, f0_ - h0_) >> 16); \
    u32 u1_ = (RG1)[i_]; float f1_ = __builtin_bit_cast(float, u1_); \
    float h1_ = __builtin_bit_cast(float, u1_ & 0xffff0000u); \
    (AH)[4 + i_] = (short)(u1_ >> 16); \
    (AL)[4 + i_] = (short)(__builtin_bit_cast(u32, f1_ - h1_) >> 16); } }

// consume chunk J from RG; VMC = vmcnt literal string; ISEMB = 1 for emb chunks
#define CONSUME(J, RG, VMC, ISEMB) { \
  asm volatile("s_waitcnt vmcnt(" VMC ")" ::: "memory"); \
  __builtin_amdgcn_sched_barrier(0); \
  v8s b0h_ = __builtin_bit_cast(v8s, RG[8]); \
  v8s b0l_ = __builtin_bit_cast(v8s, RG[9]); \
  v8s b1h_ = __builtin_bit_cast(v8s, RG[10]); \
  v8s b1l_ = __builtin_bit_cast(v8s, RG[11]); \
  _Pragma("unroll") for (int mt_ = 0; mt_ < 4; ++mt_) { \
    v8s ah_, al_; \
    if (ISEMB) { CVT8(RG[2 * mt_], RG[2 * mt_ + 1], ah_, al_); } \
    else { ah_ = __builtin_bit_cast(v8s, RG[2 * mt_]); \
           al_ = __builtin_bit_cast(v8s, RG[2 * mt_ + 1]); } \
    acc[mt_][0] = MFMA16(ah_, b0h_, acc[mt_][0]); \
    acc[mt_][0] = MFMA16(ah_, b0l_, acc[mt_][0]); \
    acc[mt_][0] = MFMA16(al_, b0h_, acc[mt_][0]); \
    acc[mt_][1] = MFMA16(ah_, b1h_, acc[mt_][1]); \
    acc[mt_][1] = MFMA16(ah_, b1l_, acc[mt_][1]); \
    acc[mt_][1] = MFMA16(al_, b1h_, acc[mt_][1]); } }

// ---------------- persistent recurrence kernel ----------------
// 64 WGs x 256 thr, WG g owns hidden units [g*8, g*8+8) (gate cols i,f,g,o).
// Waves split K (6 chunks each); cross-wave reduce in LDS; flag-sync per step.
__global__ __launch_bounds__(256, 1) void k_lstm(
    const int* __restrict__ xin, const float* __restrict__ emb,
    const float* __restrict__ bih, const float* __restrict__ bhh,
    uint8_t* __restrict__ ws, float* __restrict__ dout)
{
  const int wg = blockIdx.x;
  const int tid = threadIdx.x;
  const int wv = tid >> 6;    // wave 0..3
  const int lane = tid & 63;
  const int cl = lane & 15;   // m-in-tile / col-in-tile
  const int gq = lane >> 4;   // k-group

  u32* flags = (u32*)(ws + OFF_FLAGS);
  u16* hhi = (u16*)(ws + OFF_HHI);
  u16* hlo = (u16*)(ws + OFF_HLO);
  const u16* wf = (const u16*)(ws + OFF_WF);

  __shared__ f32x4 red[4][4][2][64];   // [src_wave][mtile][ntile][lane]

  float bias[2];
#pragma unroll
  for (int nt = 0; nt < 2; ++nt) {
    int n32 = nt * 16 + cl;
    int R = (n32 >> 3) * 512 + wg * 8 + (n32 & 7);
    bias[nt] = bih[R] + bhh[R];
  }

  float cst[4] = {0.f, 0.f, 0.f, 0.f};  // c-state (valid on lanes cl<8)
  u32x4 rgA[12], rgB[12];

  for (int t = 0; t < 512; ++t) {
    const u16* hc_hi = hhi + (t & 1) * 32768;
    const u16* hc_lo = hlo + (t & 1) * 32768;
    u16* hn_hi = hhi + ((t & 1) ^ 1) * 32768;
    u16* hn_lo = hlo + ((t & 1) ^ 1) * 32768;

    // embedding row pointers for the 4 m-tiles (token (b=m, t)); row 0 is zeros
    const float* ebase0 = emb + (size_t)xin[(0 * 16 + cl) * 512 + t] * 256;
    const float* ebase1 = emb + (size_t)xin[(1 * 16 + cl) * 512 + t] * 256;
    const float* ebase2 = emb + (size_t)xin[(2 * 16 + cl) * 512 + t] * 256;
    const float* ebase3 = emb + (size_t)xin[(3 * 16 + cl) * 512 + t] * 256;

    // issue emb chunks before the poll (latency hidden under flag wait)
    ISSUE_E(0, rgA);
    ISSUE_E(1, rgB);

    // wait for all 64 producer slices of h_{t-1}
    {
      const u32* fl = flags + (size_t)t * 64;
      while (true) {
        u32 f = __hip_atomic_load(fl + lane, __ATOMIC_RELAXED, __HIP_MEMORY_SCOPE_AGENT);
        if (__all(f != 0)) break;
        __builtin_amdgcn_s_sleep(2);
      }
    }

    f32x4 acc[4][2] = {};

    CONSUME(0, rgA, "12", 1);  ISSUE_H(2, rgA);
    CONSUME(1, rgB, "12", 1);  ISSUE_H(3, rgB);
    CONSUME(2, rgA, "12", 0);  ISSUE_H(4, rgA);
    CONSUME(3, rgB, "12", 0);  ISSUE_H(5, rgB);
    CONSUME(4, rgA, "12", 0);
    CONSUME(5, rgB, "0", 0);

    // cross-wave K-reduction through LDS
#pragma unroll
    for (int mt = 0; mt < 4; ++mt) {
      red[wv][mt][0][lane] = acc[mt][0];
      red[wv][mt][1][lane] = acc[mt][1];
    }
    __syncthreads();
    f32x4 fin0 = red[0][wv][0][lane] + red[1][wv][0][lane] + red[2][wv][0][lane] + red[3][wv][0][lane];
    f32x4 fin1 = red[0][wv][1][lane] + red[1][wv][1][lane] + red[2][wv][1][lane] + red[3][wv][1][lane];
    fin0 += bias[0];
    fin1 += bias[1];

    // gate math: cols [i(0..7) f(8..15)] in fin0, [g(0..7) o(8..15)] in fin1
#pragma unroll
    for (int r = 0; r < 4; ++r) {
      float iv = fin0[r];
      float gv = fin1[r];
      float fv = __shfl_xor(iv, 8, 64);   // partner holds f (resp. o) column
      float ov = __shfl_xor(gv, 8, 64);
      float ii = sigm(iv);
      float ff = sigm(fv);
      float gg = tanhf_fast(gv);
      float oo = sigm(ov);
      float cn = ff * cst[r] + ii * gg;
      cst[r] = cn;
      float hn = oo * tanhf_fast(cn);
      if (cl < 8) {
        int j = wg * 8 + cl;
        int m = wv * 16 + 4 * gq + r;
        if (t < 511) {
          u16 hi = bf_hi(hn);
          float lo = hn - bf_up(hi);
          u32 hiw = hi, low = bf_hi(lo);
          STORES_C(hn_hi + m * 512 + j, hiw);
          STORES_C(hn_lo + m * 512 + j, low);
        } else {
          dout[320 + m * 512 + j] = hn;           // h_t
          dout[320 + 32768 + m * 512 + j] = cn;   // c_t
        }
      }
    }

    // drain our asm stores (compiler doesn't know about them), then barrier+flag
    asm volatile("s_waitcnt vmcnt(0)" ::: "memory");
    __syncthreads();
    if (t < 511 && tid == 0) {
      __hip_atomic_store(flags + (size_t)(t + 1) * 64 + wg, 1u,
                         __ATOMIC_RELEASE, __HIP_MEMORY_SCOPE_AGENT);
    }
  }
}

// ---------------- final projection: out = h_T @ W_out^T + b_out ----------------
__global__ void k_out(const float* __restrict__ Wout, const float* __restrict__ bout,
                      float* __restrict__ dout) {
  int i = threadIdx.x;
  if (i >= 320) return;
  int b = i / 5, o = i - b * 5;
  const float* hp = dout + 320 + b * 512;
  const float* wp = Wout + (size_t)o * 512;
  float s = 0.f;
#pragma unroll 4
  for (int k = 0; k < 512; k += 4) {
    s += hp[k] * wp[k] + hp[k + 1] * wp[k + 1] + hp[k + 2] * wp[k + 2] + hp[k + 3] * wp[k + 3];
  }
  dout[i] = s + bout[o];
}

extern "C" void kernel_launch(void* const* d_in, const int* in_sizes, int n_in,
                              void* d_out, int out_size, void* d_ws, size_t ws_size,
                              hipStream_t stream) {
  const int* x = (const int*)d_in[0];
  const float* emb = (const float*)d_in[1];
  const float* Wih = (const float*)d_in[2];
  const float* bih = (const float*)d_in[3];
  const float* Whh = (const float*)d_in[4];
  const float* bhh = (const float*)d_in[5];
  const float* Wout = (const float*)d_in[6];
  const float* bout = (const float*)d_in[7];
  float* out = (float*)d_out;
  uint8_t* ws = (uint8_t*)d_ws;

  hipLaunchKernelGGL(k_init, dim3(384), dim3(256), 0, stream, (u32*)ws);
  hipLaunchKernelGGL(k_prep, dim3(768), dim3(256), 0, stream, Wih, Whh, (u16*)(ws + OFF_WF));
  hipLaunchKernelGGL(k_lstm, dim3(64), dim3(256), 0, stream, x, emb, bih, bhh, ws, out);
  hipLaunchKernelGGL(k_out, dim3(1), dim3(320), 0, stream, Wout, bout, out);
}

// Round 4
// 4388.456 us; speedup vs baseline: 1.0487x; 1.0487x over previous
//
#include <hip/hip_runtime.h>
#include <stdint.h>

typedef unsigned short u16;
typedef uint32_t u32;
typedef __attribute__((ext_vector_type(4))) u32 u32x4;
typedef __attribute__((ext_vector_type(8))) short v8s;
typedef __attribute__((ext_vector_type(4))) float f32x4;

// ---------------- workspace layout (bytes) ----------------
// flags : u32 [512][64]              @ 0        (131072 B)
// h_hi  : u16 [2][64][512]           @ 131072   (131072 B)
// h_lo  : u16 [2][64][512]           @ 262144   (131072 B)
// wf    : u16 [64][2][24][64][16]    @ 393216   (6291456 B)
#define OFF_FLAGS 0
#define OFF_HHI   131072
#define OFF_HLO   262144
#define OFF_WF    393216

__device__ __forceinline__ u16 bf_hi(float v) {
  return (u16)(__builtin_bit_cast(u32, v) >> 16);
}
__device__ __forceinline__ float bf_up(u16 h) {
  return __builtin_bit_cast(float, (u32)h << 16);
}
__device__ __forceinline__ float tanhf_fast(float x) {
  float e = __expf(2.f * x);
  return 1.f - 2.f / (e + 1.f);
}
__device__ __forceinline__ float sigm(float x) {
  return 1.f / (1.f + __expf(-x));
}

// ---------------- init: zero flags + h buffers, set flags row 0 --------------
__global__ void k_init(u32* w) {
  int i = blockIdx.x * 256 + threadIdx.x;   // 98304 u32 (flags + h_hi + h_lo)
  if (i < 98304) w[i] = (i < 64) ? 1u : 0u; // flags[0][0..63] = 1 (h0 ready)
}

// ---------------- pre-pack W_ih / W_hh into MFMA fragment order, bf16 hi/lo --
// chunk c: 0..7 -> W_ih (K'=c*32), 8..23 -> W_hh (K=(c-8)*32)
// B[k][n32] = W[R(n32)][k], R(n32) = (n32>>3)*512 + wg*8 + (n32&7)
__global__ void k_prep(const float* __restrict__ Wih, const float* __restrict__ Whh,
                       u16* __restrict__ wf) {
  int idx = blockIdx.x * 256 + threadIdx.x;
  if (idx >= 64 * 2 * 24 * 64) return;
  int lane = idx & 63;
  int r1 = idx >> 6;
  int c  = r1 % 24;
  int r2 = r1 / 24;
  int nt = r2 & 1;
  int wg = r2 >> 1;
  int n32 = nt * 16 + (lane & 15);
  int R = (n32 >> 3) * 512 + wg * 8 + (n32 & 7);
  int gq = lane >> 4;
  const float* src = (c < 8) ? (Wih + (size_t)R * 256 + c * 32 + 8 * gq)
                             : (Whh + (size_t)R * 512 + (c - 8) * 32 + 8 * gq);
  u16* d = wf + (size_t)idx * 16;
#pragma unroll
  for (int i = 0; i < 8; ++i) {
    float v = src[i];
    u16 hi = bf_hi(v);
    float lo = v - bf_up(hi);
    d[i] = hi;
    d[8 + i] = bf_hi(lo);
  }
}

// ---------------- asm helpers (ONLY h loads/stores use asm) ------------------
#define LOADC(DST, PTR) \
  asm volatile("global_load_dwordx4 %0, %1, off sc0 sc1" : "=v"(DST) : "v"(PTR))
#define STOREC4(PTR, VAL) \
  asm volatile("global_store_dwordx4 %0, %1, off sc0 sc1" :: "v"(PTR), "v"(VAL) : "memory")

#define WAITV_(N) { asm volatile("s_waitcnt vmcnt(" #N ")" ::: "memory"); \
                    __builtin_amdgcn_sched_barrier(0); }
#define WAITV(N) WAITV_(N)

#define MFMA16(a, b, c) __builtin_amdgcn_mfma_f32_16x16x32_bf16((a), (b), (c), 0, 0, 0)
#define BC(x) __builtin_bit_cast(v8s, x)

// two f32x4 -> one (hi,lo) bf16 fragment pair
#define CVTPAIR(F0, F1, AH, AL) { \
  _Pragma("unroll") for (int i_ = 0; i_ < 4; ++i_) { \
    float f0_ = (F0)[i_]; u32 u0_ = __builtin_bit_cast(u32, f0_); \
    float h0_ = __builtin_bit_cast(float, u0_ & 0xffff0000u); \
    (AH)[i_] = (short)(u0_ >> 16); \
    (AL)[i_] = (short)(__builtin_bit_cast(u32, f0_ - h0_) >> 16); \
    float f1_ = (F1)[i_]; u32 u1_ = __builtin_bit_cast(u32, f1_); \
    float h1_ = __builtin_bit_cast(float, u1_ & 0xffff0000u); \
    (AH)[4 + i_] = (short)(u1_ >> 16); \
    (AL)[4 + i_] = (short)(__builtin_bit_cast(u32, f1_ - h1_) >> 16); } }

// issue 8 coherent h-fragment loads for h-chunk j into HA[B]
#define ISSUE_HH(j, B) { \
  const int ko_ = (wv + 4 * (j)) * 32 + 8 * gq; \
  LOADC(HA[B][0], hchi + (0*16+cl)*512 + ko_); LOADC(HA[B][1], hclo + (0*16+cl)*512 + ko_); \
  LOADC(HA[B][2], hchi + (1*16+cl)*512 + ko_); LOADC(HA[B][3], hclo + (1*16+cl)*512 + ko_); \
  LOADC(HA[B][4], hchi + (2*16+cl)*512 + ko_); LOADC(HA[B][5], hclo + (2*16+cl)*512 + ko_); \
  LOADC(HA[B][6], hchi + (3*16+cl)*512 + ko_); LOADC(HA[B][7], hclo + (3*16+cl)*512 + ko_); }

#define CONSUME_H(j, B, VMC) { \
  WAITV(VMC); \
  v8s b0h_ = BC(BH[j][0]), b0l_ = BC(BH[j][1]), b1h_ = BC(BH[j][2]), b1l_ = BC(BH[j][3]); \
  _Pragma("unroll") for (int mt_ = 0; mt_ < 4; ++mt_) { \
    v8s ah_ = BC(HA[B][2*mt_]); v8s al_ = BC(HA[B][2*mt_+1]); \
    acc[mt_][0] = MFMA16(ah_, b0h_, acc[mt_][0]); \
    acc[mt_][0] = MFMA16(ah_, b0l_, acc[mt_][0]); \
    acc[mt_][0] = MFMA16(al_, b0h_, acc[mt_][0]); \
    acc[mt_][1] = MFMA16(ah_, b1h_, acc[mt_][1]); \
    acc[mt_][1] = MFMA16(ah_, b1l_, acc[mt_][1]); \
    acc[mt_][1] = MFMA16(al_, b1h_, acc[mt_][1]); } }

#define CONSUME_E(J) { \
  v8s b0h_ = BC(WB[J][0]), b0l_ = BC(WB[J][1]), b1h_ = BC(WB[J][2]), b1l_ = BC(WB[J][3]); \
  _Pragma("unroll") for (int mt_ = 0; mt_ < 4; ++mt_) { \
    v8s ah_ = eah[J][mt_], al_ = eal[J][mt_]; \
    acc[mt_][0] = MFMA16(ah_, b0h_, acc[mt_][0]); \
    acc[mt_][0] = MFMA16(ah_, b0l_, acc[mt_][0]); \
    acc[mt_][0] = MFMA16(al_, b0h_, acc[mt_][0]); \
    acc[mt_][1] = MFMA16(ah_, b1h_, acc[mt_][1]); \
    acc[mt_][1] = MFMA16(ah_, b1l_, acc[mt_][1]); \
    acc[mt_][1] = MFMA16(al_, b1h_, acc[mt_][1]); } }

// ---------------- persistent recurrence kernel ----------------
// 64 WGs x 256 thr; WG g owns hidden units [g*8, g*8+8) (x4 gates).
// Waves split K (6 chunks each); cross-wave reduce in LDS; flag-sync per step.
// Emb-projection MFMAs run BEFORE the poll (independent of h).
__global__ __launch_bounds__(256, 1) void k_lstm(
    const int* __restrict__ xin, const float* __restrict__ emb,
    const float* __restrict__ bih, const float* __restrict__ bhh,
    uint8_t* __restrict__ ws, float* __restrict__ dout)
{
  const int wg = blockIdx.x;
  const int tid = threadIdx.x;
  const int wv = tid >> 6;
  const int lane = tid & 63;
  const int cl = lane & 15;
  const int gq = lane >> 4;

  u32* flags = (u32*)(ws + OFF_FLAGS);
  u16* hhi = (u16*)(ws + OFF_HHI);
  u16* hlo = (u16*)(ws + OFF_HLO);
  const u16* wf = (const u16*)(ws + OFF_WF);

  __shared__ f32x4 red[4][4][2][64];                 // 32 KiB
  __shared__ alignas(16) u16 lds_hh[64][8];          // 1 KiB
  __shared__ alignas(16) u16 lds_hl[64][8];          // 1 KiB

  float bias[2];
#pragma unroll
  for (int nt = 0; nt < 2; ++nt) {
    int n32 = nt * 16 + cl;
    int R = (n32 >> 3) * 512 + wg * 8 + (n32 & 7);
    bias[nt] = bih[R] + bhh[R];
  }

  // resident B-fragments via NORMAL loads (compiler-managed; AGPR-safe):
  // W_hh chunks (8 + wv + 4j), W_ih chunks (4J + wv); each {b0h,b0l,b1h,b1l}
  u32x4 BH[4][4], WB[2][4];
#pragma unroll
  for (int j = 0; j < 4; ++j) {
    const u32x4* p0 = (const u32x4*)(wf + ((((size_t)wg*2+0)*24 + (8 + wv + 4*j))*64 + lane)*16);
    const u32x4* p1 = (const u32x4*)(wf + ((((size_t)wg*2+1)*24 + (8 + wv + 4*j))*64 + lane)*16);
    BH[j][0] = p0[0]; BH[j][1] = p0[1];
    BH[j][2] = p1[0]; BH[j][3] = p1[1];
  }
#pragma unroll
  for (int J = 0; J < 2; ++J) {
    const u32x4* p0 = (const u32x4*)(wf + ((((size_t)wg*2+0)*24 + (4*J + wv))*64 + lane)*16);
    const u32x4* p1 = (const u32x4*)(wf + ((((size_t)wg*2+1)*24 + (4*J + wv))*64 + lane)*16);
    WB[J][0] = p0[0]; WB[J][1] = p0[1];
    WB[J][2] = p1[0]; WB[J][3] = p1[1];
  }

  const int koA = wv * 32 + 8 * gq;         // emb chunk J=0 (chunk wv)
  const int koB = (4 + wv) * 32 + 8 * gq;   // emb chunk J=1 (chunk 4+wv)

  // emb prefetch buffer (normal loads) + t=0 issue
  f32x4 EA[16];
  {
    const float* e0 = emb + (size_t)xin[(0*16+cl)*512] * 256;
    const float* e1 = emb + (size_t)xin[(1*16+cl)*512] * 256;
    const float* e2 = emb + (size_t)xin[(2*16+cl)*512] * 256;
    const float* e3 = emb + (size_t)xin[(3*16+cl)*512] * 256;
    EA[0] = *(const f32x4*)(e0 + koA); EA[1] = *(const f32x4*)(e0 + koA + 4);
    EA[2] = *(const f32x4*)(e1 + koA); EA[3] = *(const f32x4*)(e1 + koA + 4);
    EA[4] = *(const f32x4*)(e2 + koA); EA[5] = *(const f32x4*)(e2 + koA + 4);
    EA[6] = *(const f32x4*)(e3 + koA); EA[7] = *(const f32x4*)(e3 + koA + 4);
    EA[8]  = *(const f32x4*)(e0 + koB); EA[9]  = *(const f32x4*)(e0 + koB + 4);
    EA[10] = *(const f32x4*)(e1 + koB); EA[11] = *(const f32x4*)(e1 + koB + 4);
    EA[12] = *(const f32x4*)(e2 + koB); EA[13] = *(const f32x4*)(e2 + koB + 4);
    EA[14] = *(const f32x4*)(e3 + koB); EA[15] = *(const f32x4*)(e3 + koB + 4);
  }
  WAITV(0);   // prologue drain: BH/WB/EA resident; vmcnt clean at loop entry

  float cst[4] = {0.f, 0.f, 0.f, 0.f};

  for (int t = 0; t < 512; ++t) {
    // ---- pre-poll: emb projection for step t (independent of h) ----
    v8s eah[2][4], eal[2][4];
#pragma unroll
    for (int mt = 0; mt < 4; ++mt) {
      CVTPAIR(EA[2*mt], EA[2*mt+1], eah[0][mt], eal[0][mt]);
      CVTPAIR(EA[8+2*mt], EA[8+2*mt+1], eah[1][mt], eal[1][mt]);
    }
    f32x4 acc[4][2] = {};
    CONSUME_E(0); CONSUME_E(1);

    // reissue EA for step t+1 (old EA dead; drains inside the poll below)
    {
      const int tp = (t + 1) & 511;
      const float* e0 = emb + (size_t)xin[(0*16+cl)*512 + tp] * 256;
      const float* e1 = emb + (size_t)xin[(1*16+cl)*512 + tp] * 256;
      const float* e2 = emb + (size_t)xin[(2*16+cl)*512 + tp] * 256;
      const float* e3 = emb + (size_t)xin[(3*16+cl)*512 + tp] * 256;
      EA[0] = *(const f32x4*)(e0 + koA); EA[1] = *(const f32x4*)(e0 + koA + 4);
      EA[2] = *(const f32x4*)(e1 + koA); EA[3] = *(const f32x4*)(e1 + koA + 4);
      EA[4] = *(const f32x4*)(e2 + koA); EA[5] = *(const f32x4*)(e2 + koA + 4);
      EA[6] = *(const f32x4*)(e3 + koA); EA[7] = *(const f32x4*)(e3 + koA + 4);
      EA[8]  = *(const f32x4*)(e0 + koB); EA[9]  = *(const f32x4*)(e0 + koB + 4);
      EA[10] = *(const f32x4*)(e1 + koB); EA[11] = *(const f32x4*)(e1 + koB + 4);
      EA[12] = *(const f32x4*)(e2 + koB); EA[13] = *(const f32x4*)(e2 + koB + 4);
      EA[14] = *(const f32x4*)(e3 + koB); EA[15] = *(const f32x4*)(e3 + koB + 4);
    }

    const u16* hchi = hhi + (t & 1) * 32768;
    const u16* hclo = hlo + (t & 1) * 32768;
    u16* hnhi = hhi + ((t & 1) ^ 1) * 32768;
    u16* hnlo = hlo + ((t & 1) ^ 1) * 32768;

    // ---- poll for h_{t-1}; atomic load forces vmcnt(0) -> EA drained too ----
    {
      const u32* fl = flags + (size_t)t * 64;
      while (true) {
        u32 f = __hip_atomic_load(fl + lane, __ATOMIC_RELAXED, __HIP_MEMORY_SCOPE_AGENT);
        if (__all(f != 0)) break;
        __builtin_amdgcn_s_sleep(1);
      }
    }
    __builtin_amdgcn_sched_barrier(0);

    // ---- h phase: counted-vmcnt asm region (only HA loads outstanding) ----
    u32x4 HA[2][8];
    ISSUE_HH(0, 0); ISSUE_HH(1, 1);
    CONSUME_H(0, 0, 8);  ISSUE_HH(2, 0);
    CONSUME_H(1, 1, 8);  ISSUE_HH(3, 1);
    CONSUME_H(2, 0, 8);
    CONSUME_H(3, 1, 0);
    __builtin_amdgcn_sched_barrier(0);

    // ---- cross-wave K-reduction through LDS ----
#pragma unroll
    for (int mt = 0; mt < 4; ++mt) {
      red[wv][mt][0][lane] = acc[mt][0];
      red[wv][mt][1][lane] = acc[mt][1];
    }
    __syncthreads();
    f32x4 fin0 = red[0][wv][0][lane] + red[1][wv][0][lane] + red[2][wv][0][lane] + red[3][wv][0][lane];
    f32x4 fin1 = red[0][wv][1][lane] + red[1][wv][1][lane] + red[2][wv][1][lane] + red[3][wv][1][lane];
    fin0 += bias[0];
    fin1 += bias[1];

    // ---- gates: cols [i(0..7) f(8..15)] in fin0, [g(0..7) o(8..15)] in fin1
#pragma unroll
    for (int r = 0; r < 4; ++r) {
      float iv = fin0[r];
      float gv = fin1[r];
      float fv = __shfl_xor(iv, 8, 64);
      float ov = __shfl_xor(gv, 8, 64);
      float ii = sigm(iv);
      float ff = sigm(fv);
      float gg = tanhf_fast(gv);
      float oo = sigm(ov);
      float cn = ff * cst[r] + ii * gg;
      cst[r] = cn;
      float hn = oo * tanhf_fast(cn);
      if (cl < 8) {
        int m = wv * 16 + 4 * gq + r;
        if (t < 511) {
          u16 hi = bf_hi(hn);
          float lo = hn - bf_up(hi);
          lds_hh[m][cl] = hi;
          lds_hl[m][cl] = bf_hi(lo);
        } else {
          int j = wg * 8 + cl;
          dout[320 + m * 512 + j] = hn;            // h_t
          dout[320 + 32768 + m * 512 + j] = cn;    // c_t
        }
      }
    }

    if (t < 511) {
      __syncthreads();                              // pack visible
      if (wv == 0) {
        u32x4 v_ = *(const u32x4*)&lds_hh[lane][0];
        STOREC4(hnhi + lane * 512 + wg * 8, v_);
      } else if (wv == 1) {
        u32x4 v_ = *(const u32x4*)&lds_hl[lane][0];
        STOREC4(hnlo + lane * 512 + wg * 8, v_);
      }
      WAITV(0);                                     // h stores globally complete
      __syncthreads();                              // all waves drained; red reads done
      if (tid == 0)
        __hip_atomic_store(flags + (size_t)(t + 1) * 64 + wg, 1u,
                           __ATOMIC_RELAXED, __HIP_MEMORY_SCOPE_AGENT);
    }
  }
}

// ---------------- final projection: out = h_T @ W_out^T + b_out --------------
__global__ void k_out(const float* __restrict__ Wout, const float* __restrict__ bout,
                      float* __restrict__ dout) {
  int i = threadIdx.x;
  if (i >= 320) return;
  int b = i / 5, o = i - b * 5;
  const float* hp = dout + 320 + b * 512;
  const float* wp = Wout + (size_t)o * 512;
  float s = 0.f;
#pragma unroll 4
  for (int k = 0; k < 512; k += 4) {
    s += hp[k] * wp[k] + hp[k + 1] * wp[k + 1] + hp[k + 2] * wp[k + 2] + hp[k + 3] * wp[k + 3];
  }
  dout[i] = s + bout[o];
}

extern "C" void kernel_launch(void* const* d_in, const int* in_sizes, int n_in,
                              void* d_out, int out_size, void* d_ws, size_t ws_size,
                              hipStream_t stream) {
  const int* x = (const int*)d_in[0];
  const float* emb = (const float*)d_in[1];
  const float* Wih = (const float*)d_in[2];
  const float* bih = (const float*)d_in[3];
  const float* Whh = (const float*)d_in[4];
  const float* bhh = (const float*)d_in[5];
  const float* Wout = (const float*)d_in[6];
  const float* bout = (const float*)d_in[7];
  float* out = (float*)d_out;
  uint8_t* ws = (uint8_t*)d_ws;

  hipLaunchKernelGGL(k_init, dim3(384), dim3(256), 0, stream, (u32*)ws);
  hipLaunchKernelGGL(k_prep, dim3(768), dim3(256), 0, stream, Wih, Whh, (u16*)(ws + OFF_WF));
  hipLaunchKernelGGL(k_lstm, dim3(64), dim3(256), 0, stream, x, emb, bih, bhh, ws, out);
  hipLaunchKernelGGL(k_out, dim3(1), dim3(320), 0, stream, Wout, bout, out);
}

// Round 5
// 2538.189 us; speedup vs baseline: 1.8131x; 1.7290x over previous
//
#include <hip/hip_runtime.h>
#include <stdint.h>

typedef unsigned short u16;
typedef uint32_t u32;
typedef __attribute__((ext_vector_type(4))) u32 u32x4;
typedef __attribute__((ext_vector_type(8))) short v8s;
typedef __attribute__((ext_vector_type(4))) float f32x4;

// ---------------- workspace layout (bytes) ----------------
// h  : u32 [2 buf][4 group][16 row][512 hid]   @ 0        (262144 B)
//      word = (bf16_hi << 16) | (bf16_lo & 0xFFFE) | tagbit,  tag = (t>>1)&1
// wf : u16 [64][2][24][64][16]                 @ 262144   (6291456 B)
#define OFF_H  0
#define OFF_WF 262144

__device__ __forceinline__ u16 bf_hi(float v) {
  return (u16)(__builtin_bit_cast(u32, v) >> 16);
}
__device__ __forceinline__ float bf_up(u16 h) {
  return __builtin_bit_cast(float, (u32)h << 16);
}
__device__ __forceinline__ float tanhf_fast(float x) {
  float e = __expf(2.f * x);
  return 1.f - 2.f / (e + 1.f);
}
__device__ __forceinline__ float sigm(float x) {
  return 1.f / (1.f + __expf(-x));
}

// ---------------- init: buf0 = 0 (h0, tag 0 valid), buf1 = 1 (tag 1, invalid at t=1)
__global__ void k_init(u32* h) {
  int i = blockIdx.x * 256 + threadIdx.x;   // 65536 words
  if (i < 65536) h[i] = (i < 32768) ? 0u : 1u;
}

// ---------------- pre-pack W_ih / W_hh into MFMA fragment order, bf16 hi/lo --
// chunk c: 0..7 -> W_ih (K'=c*32), 8..23 -> W_hh (K=(c-8)*32)
// B[k][n32] = W[R(n32)][k], R(n32) = (n32>>3)*512 + wg*8 + (n32&7)
__global__ void k_prep(const float* __restrict__ Wih, const float* __restrict__ Whh,
                       u16* __restrict__ wf) {
  int idx = blockIdx.x * 256 + threadIdx.x;
  if (idx >= 64 * 2 * 24 * 64) return;
  int lane = idx & 63;
  int r1 = idx >> 6;
  int c  = r1 % 24;
  int r2 = r1 / 24;
  int nt = r2 & 1;
  int wg = r2 >> 1;
  int n32 = nt * 16 + (lane & 15);
  int R = (n32 >> 3) * 512 + wg * 8 + (n32 & 7);
  int gq = lane >> 4;
  const float* src = (c < 8) ? (Wih + (size_t)R * 256 + c * 32 + 8 * gq)
                             : (Whh + (size_t)R * 512 + (c - 8) * 32 + 8 * gq);
  u16* d = wf + (size_t)idx * 16;
#pragma unroll
  for (int i = 0; i < 8; ++i) {
    float v = src[i];
    u16 hi = bf_hi(v);
    float lo = v - bf_up(hi);
    d[i] = hi;
    d[8 + i] = bf_hi(lo);
  }
}

// ---------------- asm helpers (only tagged h traffic uses asm) ---------------
#define LOADC(DST, PTR) \
  asm volatile("global_load_dwordx4 %0, %1, off sc0 sc1" : "=v"(DST) : "v"(PTR))
#define STORED(PTR, VAL) \
  asm volatile("global_store_dword %0, %1, off sc0 sc1" :: "v"(PTR), "v"(VAL) : "memory")

#define WAITV_(N) { asm volatile("s_waitcnt vmcnt(" #N ")" ::: "memory"); \
                    __builtin_amdgcn_sched_barrier(0); }
#define WAITV(N) WAITV_(N)

#define MFMA16(a, b, c) __builtin_amdgcn_mfma_f32_16x16x32_bf16((a), (b), (c), 0, 0, 0)
#define BC(x) __builtin_bit_cast(v8s, x)

#define PKHI(a, b) (((b) & 0xffff0000u) | ((a) >> 16))
#define PKLO(a, b) (((b) << 16) | ((a) & 0xffffu))

// two f32x4 -> one (hi,lo) bf16 fragment pair
#define CVTPAIR(F0, F1, AH, AL) { \
  _Pragma("unroll") for (int i_ = 0; i_ < 4; ++i_) { \
    float f0_ = (F0)[i_]; u32 u0_ = __builtin_bit_cast(u32, f0_); \
    float h0_ = __builtin_bit_cast(float, u0_ & 0xffff0000u); \
    (AH)[i_] = (short)(u0_ >> 16); \
    (AL)[i_] = (short)(__builtin_bit_cast(u32, f0_ - h0_) >> 16); \
    float f1_ = (F1)[i_]; u32 u1_ = __builtin_bit_cast(u32, f1_); \
    float h1_ = __builtin_bit_cast(float, u1_ & 0xffff0000u); \
    (AH)[4 + i_] = (short)(u1_ >> 16); \
    (AL)[4 + i_] = (short)(__builtin_bit_cast(u32, f1_ - h1_) >> 16); } }

// 6 MFMAs of one K-chunk: A (ah,al) x B {b0h,b0l,b1h,b1l} -> acc[0..1]
#define MM6(AH, AL, B) { \
  v8s b0h_ = BC((B)[0]), b0l_ = BC((B)[1]), b1h_ = BC((B)[2]), b1l_ = BC((B)[3]); \
  acc[0] = MFMA16((AH), b0h_, acc[0]); \
  acc[0] = MFMA16((AH), b0l_, acc[0]); \
  acc[0] = MFMA16((AL), b0h_, acc[0]); \
  acc[1] = MFMA16((AH), b1h_, acc[1]); \
  acc[1] = MFMA16((AH), b1l_, acc[1]); \
  acc[1] = MFMA16((AL), b1h_, acc[1]); }

// ---------------- persistent recurrence kernel ----------------
// Grid 256 = 4 batch-groups x 64 WGs. Group g owns batch rows [g*16, g*16+16);
// WG wg owns hidden units [wg*8, wg*8+8) (x4 gates). Waves split K (6 chunks).
// h exchange: per-dword tagged words, double-buffered, no flags, no atomics.
__global__ __launch_bounds__(256, 1) void k_lstm(
    const int* __restrict__ xin, const float* __restrict__ emb,
    const float* __restrict__ bih, const float* __restrict__ bhh,
    uint8_t* __restrict__ ws, float* __restrict__ dout)
{
  const int bid = blockIdx.x;
  const int wg = bid & 63;
  const int g  = bid >> 6;
  const int tid = threadIdx.x;
  const int wv = tid >> 6;
  const int lane = tid & 63;
  const int cl = lane & 15;
  const int gq = lane >> 4;

  u32* hbuf = (u32*)(ws + OFF_H);
  const u16* wf = (const u16*)(ws + OFF_WF);

  __shared__ f32x4 red[4][2][64];   // [src_wave][ntile][lane], 8 KiB

  float bias[2];
#pragma unroll
  for (int nt = 0; nt < 2; ++nt) {
    int n32 = nt * 16 + cl;
    int R = (n32 >> 3) * 512 + wg * 8 + (n32 & 7);
    bias[nt] = bih[R] + bhh[R];
  }

  // resident B-fragments (normal loads, compiler-managed):
  // W_hh chunks (8 + wv + 4j), W_ih chunks (4J + wv); each {b0h,b0l,b1h,b1l}
  u32x4 BH[4][4], WB[2][4];
#pragma unroll
  for (int j = 0; j < 4; ++j) {
    const u32x4* p0 = (const u32x4*)(wf + ((((size_t)wg*2+0)*24 + (8 + wv + 4*j))*64 + lane)*16);
    const u32x4* p1 = (const u32x4*)(wf + ((((size_t)wg*2+1)*24 + (8 + wv + 4*j))*64 + lane)*16);
    BH[j][0] = p0[0]; BH[j][1] = p0[1];
    BH[j][2] = p1[0]; BH[j][3] = p1[1];
  }
#pragma unroll
  for (int J = 0; J < 2; ++J) {
    const u32x4* p0 = (const u32x4*)(wf + ((((size_t)wg*2+0)*24 + (4*J + wv))*64 + lane)*16);
    const u32x4* p1 = (const u32x4*)(wf + ((((size_t)wg*2+1)*24 + (4*J + wv))*64 + lane)*16);
    WB[J][0] = p0[0]; WB[J][1] = p0[1];
    WB[J][2] = p1[0]; WB[J][3] = p1[1];
  }

  // emb: one batch row per lane (row = cl); two K-chunks per wave
  const int brow = g * 16 + cl;                 // this lane's batch row
  const int koA = wv * 32 + 8 * gq;             // emb chunk wv
  const int koB = (4 + wv) * 32 + 8 * gq;       // emb chunk 4+wv

  f32x4 EA[4];
  {
    const float* eb = emb + (size_t)xin[brow * 512] * 256;
    EA[0] = *(const f32x4*)(eb + koA); EA[1] = *(const f32x4*)(eb + koA + 4);
    EA[2] = *(const f32x4*)(eb + koB); EA[3] = *(const f32x4*)(eb + koB + 4);
  }

  float cst[4] = {0.f, 0.f, 0.f, 0.f};   // c-state, rows 4*gq+r (identical in all waves)

  for (int t = 0; t < 512; ++t) {
    // ---- emb projection for step t (independent of h; compiler waits EA) ----
    v8s eah[2], eal[2];
    CVTPAIR(EA[0], EA[1], eah[0], eal[0]);
    CVTPAIR(EA[2], EA[3], eah[1], eal[1]);
    f32x4 acc[2] = {};
    MM6(eah[0], eal[0], WB[0]);
    MM6(eah[1], eal[1], WB[1]);

    // reissue EA for step t+1 (drains inside the poll's vmcnt(0))
    {
      const int tp = (t + 1) & 511;
      const float* eb = emb + (size_t)xin[brow * 512 + tp] * 256;
      EA[0] = *(const f32x4*)(eb + koA); EA[1] = *(const f32x4*)(eb + koA + 4);
      EA[2] = *(const f32x4*)(eb + koB); EA[3] = *(const f32x4*)(eb + koB + 4);
    }
    __builtin_amdgcn_sched_barrier(0);

    // ---- tagged h poll: 8 dwordx4 (4 chunks), per-dword LSB tag check ----
    const u32* hc = hbuf + ((size_t)(t & 1) * 4 + g) * 8192;
    u32* hn = hbuf + ((size_t)((t + 1) & 1) * 4 + g) * 8192;
    const u32 texp = (u32)((t >> 1) & 1);
    const u32* p0 = hc + cl * 512 + (wv + 0) * 32 + 8 * gq;
    const u32* p1 = hc + cl * 512 + (wv + 4) * 32 + 8 * gq;
    const u32* p2 = hc + cl * 512 + (wv + 8) * 32 + 8 * gq;
    const u32* p3 = hc + cl * 512 + (wv + 12) * 32 + 8 * gq;

    u32x4 HA[8];
    while (true) {
      LOADC(HA[0], p0); LOADC(HA[1], p0 + 4);
      LOADC(HA[2], p1); LOADC(HA[3], p1 + 4);
      LOADC(HA[4], p2); LOADC(HA[5], p2 + 4);
      LOADC(HA[6], p3); LOADC(HA[7], p3 + 4);
      WAITV(0);
      u32 accOr = 0;
#pragma unroll
      for (int w = 0; w < 8; ++w) {
        accOr |= (HA[w][0] ^ texp); accOr |= (HA[w][1] ^ texp);
        accOr |= (HA[w][2] ^ texp); accOr |= (HA[w][3] ^ texp);
      }
      if (__all((accOr & 1u) == 0u)) break;
    }
    __builtin_amdgcn_sched_barrier(0);

    // ---- unpack + h MFMAs (chunk j uses BH[j], k = (wv+4j)*32) ----
#pragma unroll
    for (int j = 0; j < 4; ++j) {
      u32x4 w0 = HA[2 * j], w1 = HA[2 * j + 1];
      u32x4 hiw, low;
      hiw[0] = PKHI(w0[0], w0[1]); hiw[1] = PKHI(w0[2], w0[3]);
      hiw[2] = PKHI(w1[0], w1[1]); hiw[3] = PKHI(w1[2], w1[3]);
      low[0] = PKLO(w0[0], w0[1]); low[1] = PKLO(w0[2], w0[3]);
      low[2] = PKLO(w1[0], w1[1]); low[3] = PKLO(w1[2], w1[3]);
      v8s ah = BC(hiw), al = BC(low);
      MM6(ah, al, BH[j]);
    }

    // ---- cross-wave K-reduction ----
    red[wv][0][lane] = acc[0];
    red[wv][1][lane] = acc[1];
    __syncthreads();
    f32x4 fin0 = red[0][0][lane] + red[1][0][lane] + red[2][0][lane] + red[3][0][lane];
    f32x4 fin1 = red[0][1][lane] + red[1][1][lane] + red[2][1][lane] + red[3][1][lane];
    __syncthreads();                      // red reads done before next-step writes
    fin0 += bias[0];
    fin1 += bias[1];

    // ---- gates: cols [i(0..7) f(8..15)] in fin0, [g(0..7) o(8..15)] in fin1
    const u32 tagn = (u32)(((t + 1) >> 1) & 1);
#pragma unroll
    for (int r = 0; r < 4; ++r) {
      float iv = fin0[r];
      float gv = fin1[r];
      float fv = __shfl_xor(iv, 8, 64);
      float ov = __shfl_xor(gv, 8, 64);
      float ii = sigm(iv);
      float ff = sigm(fv);
      float gg = tanhf_fast(gv);
      float oo = sigm(ov);
      float cn = ff * cst[r] + ii * gg;
      cst[r] = cn;
      float hn_v = oo * tanhf_fast(cn);
      if (wv == 0 && cl < 8) {
        int row = 4 * gq + r;                       // row within group
        int jj = wg * 8 + cl;                       // hidden unit
        if (t < 511) {
          u16 hi = bf_hi(hn_v);
          u16 lo = bf_hi(hn_v - bf_up(hi));
          u32 word = ((u32)hi << 16) | ((u32)lo & 0xfffeu) | tagn;
          STORED(hn + row * 512 + jj, word);
        } else {
          int b = g * 16 + row;
          dout[320 + b * 512 + jj] = hn_v;          // h_t
          dout[320 + 32768 + b * 512 + jj] = cn;    // c_t
        }
      }
    }
  }
}

// ---------------- final projection: out = h_T @ W_out^T + b_out --------------
__global__ void k_out(const float* __restrict__ Wout, const float* __restrict__ bout,
                      float* __restrict__ dout) {
  int i = threadIdx.x;
  if (i >= 320) return;
  int b = i / 5, o = i - b * 5;
  const float* hp = dout + 320 + b * 512;
  const float* wp = Wout + (size_t)o * 512;
  float s = 0.f;
#pragma unroll 4
  for (int k = 0; k < 512; k += 4) {
    s += hp[k] * wp[k] + hp[k + 1] * wp[k + 1] + hp[k + 2] * wp[k + 2] + hp[k + 3] * wp[k + 3];
  }
  dout[i] = s + bout[o];
}

extern "C" void kernel_launch(void* const* d_in, const int* in_sizes, int n_in,
                              void* d_out, int out_size, void* d_ws, size_t ws_size,
                              hipStream_t stream) {
  const int* x = (const int*)d_in[0];
  const float* emb = (const float*)d_in[1];
  const float* Wih = (const float*)d_in[2];
  const float* bih = (const float*)d_in[3];
  const float* Whh = (const float*)d_in[4];
  const float* bhh = (const float*)d_in[5];
  const float* Wout = (const float*)d_in[6];
  const float* bout = (const float*)d_in[7];
  float* out = (float*)d_out;
  uint8_t* ws = (uint8_t*)d_ws;

  hipLaunchKernelGGL(k_init, dim3(256), dim3(256), 0, stream, (u32*)ws);
  hipLaunchKernelGGL(k_prep, dim3(768), dim3(256), 0, stream, Wih, Whh, (u16*)(ws + OFF_WF));
  hipLaunchKernelGGL(k_lstm, dim3(256), dim3(256), 0, stream, x, emb, bih, bhh, ws, out);
  hipLaunchKernelGGL(k_out, dim3(1), dim3(320), 0, stream, Wout, bout, out);
}

// Round 6
// 1716.478 us; speedup vs baseline: 2.6811x; 1.4787x over previous
//
#include <hip/hip_runtime.h>
#include <stdint.h>

typedef unsigned short u16;
typedef uint32_t u32;
typedef __attribute__((ext_vector_type(4))) u32 u32x4;
typedef __attribute__((ext_vector_type(8))) short v8s;
typedef __attribute__((ext_vector_type(4))) float f32x4;

// ---------------- workspace layout (bytes) ----------------
// h  : u32 [2 buf][4 group][16 row][512 hid]   @ 0        (262144 B)
//      word = (bf16_hi << 16) | (bf16_lo & 0xFFFE) | tagbit,  tag = (t>>1)&1
// wf : u16 [64][2][24][64][16]                 @ 262144   (6291456 B)
#define OFF_H  0
#define OFF_WF 262144

__device__ __forceinline__ u16 bf_hi(float v) {
  return (u16)(__builtin_bit_cast(u32, v) >> 16);
}
__device__ __forceinline__ float bf_up(u16 h) {
  return __builtin_bit_cast(float, (u32)h << 16);
}
__device__ __forceinline__ float tanhf_fast(float x) {
  float e = __expf(2.f * x);
  return 1.f - 2.f / (e + 1.f);
}
__device__ __forceinline__ float sigm(float x) {
  return 1.f / (1.f + __expf(-x));
}

// ---------------- init: buf0 = 0 (h0, tag 0 valid), buf1 = 1 (tag 1, invalid at t=1)
__global__ void k_init(u32* h) {
  int i = blockIdx.x * 256 + threadIdx.x;   // 65536 words
  if (i < 65536) h[i] = (i < 32768) ? 0u : 1u;
}

// ---------------- pre-pack W_ih / W_hh into MFMA fragment order, bf16 hi/lo --
// chunk c: 0..7 -> W_ih (K'=c*32), 8..23 -> W_hh (K=(c-8)*32)
// B[k][n32] = W[R(n32)][k], R(n32) = (n32>>3)*512 + wg*8 + (n32&7)
__global__ void k_prep(const float* __restrict__ Wih, const float* __restrict__ Whh,
                       u16* __restrict__ wf) {
  int idx = blockIdx.x * 256 + threadIdx.x;
  if (idx >= 64 * 2 * 24 * 64) return;
  int lane = idx & 63;
  int r1 = idx >> 6;
  int c  = r1 % 24;
  int r2 = r1 / 24;
  int nt = r2 & 1;
  int wg = r2 >> 1;
  int n32 = nt * 16 + (lane & 15);
  int R = (n32 >> 3) * 512 + wg * 8 + (n32 & 7);
  int gq = lane >> 4;
  const float* src = (c < 8) ? (Wih + (size_t)R * 256 + c * 32 + 8 * gq)
                             : (Whh + (size_t)R * 512 + (c - 8) * 32 + 8 * gq);
  u16* d = wf + (size_t)idx * 16;
#pragma unroll
  for (int i = 0; i < 8; ++i) {
    float v = src[i];
    u16 hi = bf_hi(v);
    float lo = v - bf_up(hi);
    d[i] = hi;
    d[8 + i] = bf_hi(lo);
  }
}

// ---------------- asm helpers (only tagged h traffic uses asm) ---------------
#define LOADC(DST, PTR) \
  asm volatile("global_load_dwordx4 %0, %1, off sc0 sc1" : "=v"(DST) : "v"(PTR))
#define STORED(PTR, VAL) \
  asm volatile("global_store_dword %0, %1, off sc0 sc1" :: "v"(PTR), "v"(VAL) : "memory")

#define WAITV_(N) { asm volatile("s_waitcnt vmcnt(" #N ")" ::: "memory"); \
                    __builtin_amdgcn_sched_barrier(0); }
#define WAITV(N) WAITV_(N)

#define MFMA16(a, b, c) __builtin_amdgcn_mfma_f32_16x16x32_bf16((a), (b), (c), 0, 0, 0)
#define BC(x) __builtin_bit_cast(v8s, x)

#define PKHI(a, b) (((b) & 0xffff0000u) | ((a) >> 16))
#define PKLO(a, b) (((b) << 16) | ((a) & 0xffffu))

// two f32x4 -> one (hi,lo) bf16 fragment pair
#define CVTPAIR(F0, F1, AH, AL) { \
  _Pragma("unroll") for (int i_ = 0; i_ < 4; ++i_) { \
    float f0_ = (F0)[i_]; u32 u0_ = __builtin_bit_cast(u32, f0_); \
    float h0_ = __builtin_bit_cast(float, u0_ & 0xffff0000u); \
    (AH)[i_] = (short)(u0_ >> 16); \
    (AL)[i_] = (short)(__builtin_bit_cast(u32, f0_ - h0_) >> 16); \
    float f1_ = (F1)[i_]; u32 u1_ = __builtin_bit_cast(u32, f1_); \
    float h1_ = __builtin_bit_cast(float, u1_ & 0xffff0000u); \
    (AH)[4 + i_] = (short)(u1_ >> 16); \
    (AL)[4 + i_] = (short)(__builtin_bit_cast(u32, f1_ - h1_) >> 16); } }

// 6 MFMAs of one K-chunk: A (ah,al) x B {b0h,b0l,b1h,b1l} -> acc[0..1]
#define MM6(AH, AL, B) { \
  v8s b0h_ = BC((B)[0]), b0l_ = BC((B)[1]), b1h_ = BC((B)[2]), b1l_ = BC((B)[3]); \
  acc[0] = MFMA16((AH), b0h_, acc[0]); \
  acc[0] = MFMA16((AH), b0l_, acc[0]); \
  acc[0] = MFMA16((AL), b0h_, acc[0]); \
  acc[1] = MFMA16((AH), b1h_, acc[1]); \
  acc[1] = MFMA16((AH), b1l_, acc[1]); \
  acc[1] = MFMA16((AL), b1h_, acc[1]); }

// all 8 tag LSBs of chunk j match texp (wave-uniform result)
#define TAGOK(j) ({ \
  u32 a_ = (HA[2*(j)][0]^texp) | (HA[2*(j)][1]^texp) \
         | (HA[2*(j)][2]^texp) | (HA[2*(j)][3]^texp) \
         | (HA[2*(j)+1][0]^texp) | (HA[2*(j)+1][1]^texp) \
         | (HA[2*(j)+1][2]^texp) | (HA[2*(j)+1][3]^texp); \
  __all((a_ & 1u) == 0u); })

// unpack chunk j (hi/lo bf16 from tagged dwords) + 6 MFMAs with BH[j]
#define CONSJ(j) { \
  u32x4 w0 = HA[2*(j)], w1 = HA[2*(j)+1]; \
  u32x4 hiw, low; \
  hiw[0] = PKHI(w0[0], w0[1]); hiw[1] = PKHI(w0[2], w0[3]); \
  hiw[2] = PKHI(w1[0], w1[1]); hiw[3] = PKHI(w1[2], w1[3]); \
  low[0] = PKLO(w0[0], w0[1]); low[1] = PKLO(w0[2], w0[3]); \
  low[2] = PKLO(w1[0], w1[1]); low[3] = PKLO(w1[2], w1[3]); \
  v8s ah = BC(hiw), al = BC(low); \
  MM6(ah, al, BH[j]); }

#define ISSUEJ(j) { LOADC(HA[2*(j)], pp[j]); LOADC(HA[2*(j)+1], pp[j] + 4); }

// ---------------- persistent recurrence kernel ----------------
// Grid 256 = 4 batch-groups x 64 WGs. Group g owns batch rows [g*16, g*16+16);
// WG wg owns hidden units [wg*8, wg*8+8) (x4 gates). Waves split K (6 chunks).
// h exchange: per-dword tagged words, double-buffered, chunk-pipelined poll.
__global__ __launch_bounds__(256, 1) void k_lstm(
    const int* __restrict__ xin, const float* __restrict__ emb,
    const float* __restrict__ bih, const float* __restrict__ bhh,
    uint8_t* __restrict__ ws, float* __restrict__ dout)
{
  const int bid = blockIdx.x;
  const int wg = bid & 63;
  const int g  = bid >> 6;
  const int tid = threadIdx.x;
  const int wv = tid >> 6;
  const int lane = tid & 63;
  const int cl = lane & 15;
  const int gq = lane >> 4;

  u32* hbuf = (u32*)(ws + OFF_H);
  const u16* wf = (const u16*)(ws + OFF_WF);

  __shared__ f32x4 red[2][4][2][64];   // [t&1][src_wave][ntile][lane], 16 KiB

  float bias[2];
#pragma unroll
  for (int nt = 0; nt < 2; ++nt) {
    int n32 = nt * 16 + cl;
    int R = (n32 >> 3) * 512 + wg * 8 + (n32 & 7);
    bias[nt] = bih[R] + bhh[R];
  }

  // resident B-fragments (normal loads, compiler-managed):
  // W_hh chunks (8 + wv + 4j), W_ih chunks (4J + wv); each {b0h,b0l,b1h,b1l}
  u32x4 BH[4][4], WB[2][4];
#pragma unroll
  for (int j = 0; j < 4; ++j) {
    const u32x4* p0 = (const u32x4*)(wf + ((((size_t)wg*2+0)*24 + (8 + wv + 4*j))*64 + lane)*16);
    const u32x4* p1 = (const u32x4*)(wf + ((((size_t)wg*2+1)*24 + (8 + wv + 4*j))*64 + lane)*16);
    BH[j][0] = p0[0]; BH[j][1] = p0[1];
    BH[j][2] = p1[0]; BH[j][3] = p1[1];
  }
#pragma unroll
  for (int J = 0; J < 2; ++J) {
    const u32x4* p0 = (const u32x4*)(wf + ((((size_t)wg*2+0)*24 + (4*J + wv))*64 + lane)*16);
    const u32x4* p1 = (const u32x4*)(wf + ((((size_t)wg*2+1)*24 + (4*J + wv))*64 + lane)*16);
    WB[J][0] = p0[0]; WB[J][1] = p0[1];
    WB[J][2] = p1[0]; WB[J][3] = p1[1];
  }

  // emb: one batch row per lane (row = cl); two K-chunks per wave
  const int brow = g * 16 + cl;                 // this lane's batch row
  const int koA = wv * 32 + 8 * gq;             // emb chunk wv
  const int koB = (4 + wv) * 32 + 8 * gq;       // emb chunk 4+wv

  f32x4 EA[4];
  {
    const float* eb = emb + (size_t)xin[brow * 512] * 256;
    EA[0] = *(const f32x4*)(eb + koA); EA[1] = *(const f32x4*)(eb + koA + 4);
    EA[2] = *(const f32x4*)(eb + koB); EA[3] = *(const f32x4*)(eb + koB + 4);
  }

  float cst[4] = {0.f, 0.f, 0.f, 0.f};   // c-state rows 4*gq+r (all waves identical)

  for (int t = 0; t < 512; ++t) {
    // ---- emb projection for step t (EA prefetched; compiler waits it) ----
    v8s eah[2], eal[2];
    CVTPAIR(EA[0], EA[1], eah[0], eal[0]);
    CVTPAIR(EA[2], EA[3], eah[1], eal[1]);
    f32x4 acc[2] = {};
    MM6(eah[0], eal[0], WB[0]);
    MM6(eah[1], eal[1], WB[1]);

    // next-step token index (cheap L2 hit; drained by WAITV(0) below)
    const int tok = xin[brow * 512 + ((t + 1) & 511)];

    const u32* hc = hbuf + ((size_t)(t & 1) * 4 + g) * 8192;
    u32* hn = hbuf + ((size_t)((t + 1) & 1) * 4 + g) * 8192;
    const u32 texp = (u32)((t >> 1) & 1);
    const u32* pp[4];
    pp[0] = hc + cl * 512 + (wv + 0) * 32 + 8 * gq;
    pp[1] = hc + cl * 512 + (wv + 4) * 32 + 8 * gq;
    pp[2] = hc + cl * 512 + (wv + 8) * 32 + 8 * gq;
    pp[3] = hc + cl * 512 + (wv + 12) * 32 + 8 * gq;

    // ---- chunk-pipelined tagged poll + consume ----
    u32x4 HA[8];
    WAITV(0);                       // clean vmcnt before counted region
    ISSUEJ(0); ISSUEJ(1); ISSUEJ(2); ISSUEJ(3);
    __builtin_amdgcn_sched_barrier(0);
    u32 pend = 0;
    WAITV(6); if (TAGOK(0)) { CONSJ(0); } else pend |= 1u;
    WAITV(4); if (TAGOK(1)) { CONSJ(1); } else pend |= 2u;
    WAITV(2); if (TAGOK(2)) { CONSJ(2); } else pend |= 4u;
    WAITV(0); if (TAGOK(3)) { CONSJ(3); } else pend |= 8u;
    while (pend) {
      if (pend & 1u) ISSUEJ(0);
      if (pend & 2u) ISSUEJ(1);
      if (pend & 4u) ISSUEJ(2);
      if (pend & 8u) ISSUEJ(3);
      WAITV(0);
      if (pend & 1u) { if (TAGOK(0)) { CONSJ(0); pend &= ~1u; } }
      if (pend & 2u) { if (TAGOK(1)) { CONSJ(1); pend &= ~2u; } }
      if (pend & 4u) { if (TAGOK(2)) { CONSJ(2); pend &= ~4u; } }
      if (pend & 8u) { if (TAGOK(3)) { CONSJ(3); pend &= ~8u; } }
    }
    __builtin_amdgcn_sched_barrier(0);

    // ---- reissue emb gather for t+1 (hides under reduce/gates/next poll) ----
    {
      const float* eb = emb + (size_t)tok * 256;
      EA[0] = *(const f32x4*)(eb + koA); EA[1] = *(const f32x4*)(eb + koA + 4);
      EA[2] = *(const f32x4*)(eb + koB); EA[3] = *(const f32x4*)(eb + koB + 4);
    }

    // ---- cross-wave K-reduction (double-buffered -> one barrier) ----
    red[t & 1][wv][0][lane] = acc[0];
    red[t & 1][wv][1][lane] = acc[1];
    __syncthreads();
    f32x4 fin0 = red[t & 1][0][0][lane] + red[t & 1][1][0][lane]
               + red[t & 1][2][0][lane] + red[t & 1][3][0][lane];
    f32x4 fin1 = red[t & 1][0][1][lane] + red[t & 1][1][1][lane]
               + red[t & 1][2][1][lane] + red[t & 1][3][1][lane];
    fin0 += bias[0];
    fin1 += bias[1];

    // ---- gates: cols [i(0..7) f(8..15)] in fin0, [g(0..7) o(8..15)] in fin1
    const u32 tagn = (u32)(((t + 1) >> 1) & 1);
#pragma unroll
    for (int r = 0; r < 4; ++r) {
      float iv = fin0[r];
      float gv = fin1[r];
      float fv = __shfl_xor(iv, 8, 64);
      float ov = __shfl_xor(gv, 8, 64);
      float ii = sigm(iv);
      float ff = sigm(fv);
      float gg = tanhf_fast(gv);
      float oo = sigm(ov);
      float cn = ff * cst[r] + ii * gg;
      cst[r] = cn;
      float hn_v = oo * tanhf_fast(cn);
      // wave wv stores rows 4*wv+r (gq==wv lanes) -> 4-way parallel store issue
      if (gq == wv && cl < 8) {
        int row = 4 * gq + r;                       // row within group
        int jj = wg * 8 + cl;                       // hidden unit
        if (t < 511) {
          u16 hi = bf_hi(hn_v);
          u16 lo = bf_hi(hn_v - bf_up(hi));
          u32 word = ((u32)hi << 16) | ((u32)lo & 0xfffeu) | tagn;
          STORED(hn + row * 512 + jj, word);
        } else {
          int b = g * 16 + row;
          dout[320 + b * 512 + jj] = hn_v;          // h_t
          dout[320 + 32768 + b * 512 + jj] = cn;    // c_t
        }
      }
    }
  }
}

// ---------------- final projection: out = h_T @ W_out^T + b_out --------------
__global__ void k_out(const float* __restrict__ Wout, const float* __restrict__ bout,
                      float* __restrict__ dout) {
  int i = threadIdx.x;
  if (i >= 320) return;
  int b = i / 5, o = i - b * 5;
  const float* hp = dout + 320 + b * 512;
  const float* wp = Wout + (size_t)o * 512;
  float s = 0.f;
#pragma unroll 4
  for (int k = 0; k < 512; k += 4) {
    s += hp[k] * wp[k] + hp[k + 1] * wp[k + 1] + hp[k + 2] * wp[k + 2] + hp[k + 3] * wp[k + 3];
  }
  dout[i] = s + bout[o];
}

extern "C" void kernel_launch(void* const* d_in, const int* in_sizes, int n_in,
                              void* d_out, int out_size, void* d_ws, size_t ws_size,
                              hipStream_t stream) {
  const int* x = (const int*)d_in[0];
  const float* emb = (const float*)d_in[1];
  const float* Wih = (const float*)d_in[2];
  const float* bih = (const float*)d_in[3];
  const float* Whh = (const float*)d_in[4];
  const float* bhh = (const float*)d_in[5];
  const float* Wout = (const float*)d_in[6];
  const float* bout = (const float*)d_in[7];
  float* out = (float*)d_out;
  uint8_t* ws = (uint8_t*)d_ws;

  hipLaunchKernelGGL(k_init, dim3(256), dim3(256), 0, stream, (u32*)ws);
  hipLaunchKernelGGL(k_prep, dim3(768), dim3(256), 0, stream, Wih, Whh, (u16*)(ws + OFF_WF));
  hipLaunchKernelGGL(k_lstm, dim3(256), dim3(256), 0, stream, x, emb, bih, bhh, ws, out);
  hipLaunchKernelGGL(k_out, dim3(1), dim3(320), 0, stream, Wout, bout, out);
}